// Round 6
// baseline (436.754 us; speedup 1.0000x reference)
//
#include <hip/hip_runtime.h>
#include <hip/hip_bf16.h>

typedef __attribute__((ext_vector_type(8))) short short8;
typedef __attribute__((ext_vector_type(4))) float f32x4;

#define B_   4
#define S_   2048
#define D_   1024
#define H_   16
#define HD_  64
#define M_   (B_ * S_)      // 8192
#define N3_  (3 * D_)       // 3072

#define GLDS16(g, l)                                                        \
  __builtin_amdgcn_global_load_lds(                                         \
      (const __attribute__((address_space(1))) void*)(g),                   \
      (__attribute__((address_space(3))) void*)(l), 16, 0, 0)

__device__ __forceinline__ unsigned pack_bf2(float a, float b) {
  union { __hip_bfloat16 h; unsigned short s; } ua, ub;
  ua.h = __float2bfloat16(a);
  ub.h = __float2bfloat16(b);
  return (unsigned)ua.s | ((unsigned)ub.s << 16);
}

// ---------------------------------------------------------------- casts ----
__global__ __launch_bounds__(256) void cast_f32_bf16(
    const float* __restrict__ in, __hip_bfloat16* __restrict__ out, int n) {
  int i = (blockIdx.x * 256 + threadIdx.x) * 4;
  if (i + 3 < n) {
    float4 v = *(const float4*)(in + i);
    union { ushort4 u4; __hip_bfloat16 h[4]; } p;
    p.h[0] = __float2bfloat16(v.x);
    p.h[1] = __float2bfloat16(v.y);
    p.h[2] = __float2bfloat16(v.z);
    p.h[3] = __float2bfloat16(v.w);
    *(ushort4*)(out + i) = p.u4;
  }
}

// in: [rows][cols] fp32 -> out: [cols][rows] bf16
__global__ __launch_bounds__(256) void transpose_cast(
    const float* __restrict__ in, __hip_bfloat16* __restrict__ out,
    int rows, int cols) {
  __shared__ float tile[32][33];
  int bx = blockIdx.x * 32;
  int by = blockIdx.y * 32;
  int tx = threadIdx.x, ty = threadIdx.y;   // (32, 8)
#pragma unroll
  for (int i = 0; i < 4; ++i)
    tile[ty + i * 8][tx] = in[(size_t)(by + ty + i * 8) * cols + bx + tx];
  __syncthreads();
#pragma unroll
  for (int i = 0; i < 4; ++i)
    out[(size_t)(bx + ty + i * 8) * rows + by + tx] =
        __float2bfloat16(tile[tx][ty + i * 8]);
}

// ----------------------------------------------------------------- GEMM ----
// C[M][N] = A[M][K]*Bt[N][K]^T + bias.  128x128 tile, BK=64, GLDS16 staging
// into unpadded [128][64] LDS, XOR-8 swizzle on 16B column units.
// WVT: for output cols >= 2048 (the V slice of qkv), write transposed into
// vt[(b*16+h)][d][S] instead of C (fuses the old transpose_v kernel).
__device__ inline void store_out(float* p, float v) { *p = v; }
__device__ inline void store_out(__hip_bfloat16* p, float v) {
  *p = __float2bfloat16(v);
}

template <typename OUT_T, bool WVT>
__global__ __launch_bounds__(256) void gemm_bt_bias(
    const __hip_bfloat16* __restrict__ A, const __hip_bfloat16* __restrict__ Bt,
    const float* __restrict__ bias, OUT_T* __restrict__ C,
    __hip_bfloat16* __restrict__ vt, int M, int N, int K) {
  __shared__ __align__(16) __hip_bfloat16 Alds[128 * 64];
  __shared__ __align__(16) __hip_bfloat16 Blds[128 * 64];
  const int t = threadIdx.x;
  const int wave = t >> 6, lane = t & 63;
  const int quad = lane >> 4, l15 = lane & 15;
  const int wm = (wave >> 1) * 64, wn = (wave & 1) * 64;
  const int m0 = blockIdx.y * 128, n0 = blockIdx.x * 128;

  const int rsub = lane >> 3;
  const int gc16 = (lane & 7) ^ (rsub & 7);
  const __hip_bfloat16* gA[4];
  const __hip_bfloat16* gB[4];
  __hip_bfloat16* lA[4];
  __hip_bfloat16* lB[4];
#pragma unroll
  for (int i = 0; i < 4; ++i) {
    int c = wave * 4 + i;
    int row = c * 8 + rsub;
    gA[i] = A + (size_t)(m0 + row) * K + gc16 * 8;
    gB[i] = Bt + (size_t)(n0 + row) * K + gc16 * 8;
    lA[i] = Alds + c * 512;
    lB[i] = Blds + c * 512;
  }

  f32x4 acc[4][4] = {};

  for (int k0 = 0; k0 < K; k0 += 64) {
#pragma unroll
    for (int i = 0; i < 4; ++i) {
      GLDS16(gA[i] + k0, lA[i]);
      GLDS16(gB[i] + k0, lB[i]);
    }
    __syncthreads();
#pragma unroll
    for (int kk = 0; kk < 2; ++kk) {
      const int fo = ((kk * 4 + quad) ^ (l15 & 7)) * 8;  // swizzled frag col
      short8 a[4], bfr[4];
#pragma unroll
      for (int mt = 0; mt < 4; ++mt)
        a[mt] = *(const short8*)(Alds + (wm + mt * 16 + l15) * 64 + fo);
#pragma unroll
      for (int nt = 0; nt < 4; ++nt)
        bfr[nt] = *(const short8*)(Blds + (wn + nt * 16 + l15) * 64 + fo);
#pragma unroll
      for (int mt = 0; mt < 4; ++mt)
#pragma unroll
        for (int nt = 0; nt < 4; ++nt)
          acc[mt][nt] = __builtin_amdgcn_mfma_f32_16x16x32_bf16(
              a[mt], bfr[nt], acc[mt][nt], 0, 0, 0);
    }
    __syncthreads();
  }

  if (WVT && n0 >= 2048) {
#pragma unroll
    for (int mt = 0; mt < 4; ++mt)
#pragma unroll
      for (int nt = 0; nt < 4; ++nt) {
        int col = n0 + wn + nt * 16 + l15;
        float bv = bias[col];
        int hv = (col - 2048) >> 6, d = (col - 2048) & 63;
        int row0 = m0 + wm + mt * 16 + quad * 4;
        int bidx = row0 >> 11, s = row0 & 2047;
        uint2 w;
        w.x = pack_bf2(acc[mt][nt][0] + bv, acc[mt][nt][1] + bv);
        w.y = pack_bf2(acc[mt][nt][2] + bv, acc[mt][nt][3] + bv);
        *(uint2*)(vt + ((size_t)(bidx * 16 + hv) * 64 + d) * 2048 + s) = w;
      }
  } else {
#pragma unroll
    for (int mt = 0; mt < 4; ++mt)
#pragma unroll
      for (int nt = 0; nt < 4; ++nt) {
        int col = n0 + wn + nt * 16 + l15;
        float bv = bias[col];
#pragma unroll
        for (int r = 0; r < 4; ++r) {
          int row = m0 + wm + mt * 16 + quad * 4 + r;
          store_out(C + (size_t)row * N + col, acc[mt][nt][r] + bv);
        }
      }
  }
}

// ------------------------------------------------------ flash attention ----
// S^T formulation, K/V fragments loaded DIRECTLY from global (L1/L2 absorb
// the 4x intra-block reuse; LDS only carries the P round-trip). No barriers
// in the k-loop: waves are fully independent.
__global__ __launch_bounds__(256, 4) void attn_causal(
    const __hip_bfloat16* __restrict__ qkv,
    const __hip_bfloat16* __restrict__ vt,
    __hip_bfloat16* __restrict__ ctx) {
  __shared__ __align__(16) __hip_bfloat16 Plds[4][16][68];  // [wave][qrow][kpos]

  const int t = threadIdx.x;
  const int wave = t >> 6, lane = t & 63;
  const int quad = lane >> 4, l15 = lane & 15;
  const int xb = blockIdx.x, h = blockIdx.y, b = blockIdx.z;

  const size_t qbase = (size_t)b * S_ * N3_ + h * HD_;
  const size_t kbase = qbase + D_;
  const size_t vtbase = (size_t)(b * H_ + h) * HD_ * S_;
  const float C2 = 0.18033688f;  // (1/sqrt(64)) * log2(e)

  short8 ones;
#pragma unroll
  for (int j = 0; j < 8; ++j) ones[j] = (short)0x3F80;  // bf16 1.0

  // per-lane base pointers for direct K/V fragment loads
  const __hip_bfloat16* kp0 = qkv + kbase + (size_t)l15 * N3_ + quad * 8;
  const __hip_bfloat16* vp0 = vt + vtbase + (size_t)l15 * S_ + quad * 8;

  for (int sel = 0; sel < 2; ++sel) {
    const int qb = sel ? (31 - xb) : xb;   // pair-balanced: 33 iters/block
    const int qrow = qb * 64 + wave * 16 + l15;
    short8 qf0 = *(const short8*)(qkv + qbase + (size_t)qrow * N3_ + quad * 8);
    short8 qf1 =
        *(const short8*)(qkv + qbase + (size_t)qrow * N3_ + 32 + quad * 8);

    f32x4 o[4] = {};                 // O^T: d = dt*16+quad*4+r, col qrow=l15
    float m_r = -1e30f, l_r = 0.f;   // per-lane scalars (qrow = l15)

    for (int kb = 0; kb <= qb; ++kb) {
      const __hip_bfloat16* kp = kp0 + (size_t)(kb * 64) * N3_;
      const __hip_bfloat16* vp = vp0 + kb * 64;

      // ---- S^T = K Q^T : K frags direct from global ----
      f32x4 st[4];
#pragma unroll
      for (int nt = 0; nt < 4; ++nt) {
        short8 k0 = *(const short8*)(kp + (size_t)(nt * 16) * N3_);
        short8 k1 = *(const short8*)(kp + (size_t)(nt * 16) * N3_ + 32);
        f32x4 z = {};
        z = __builtin_amdgcn_mfma_f32_16x16x32_bf16(k0, qf0, z, 0, 0, 0);
        z = __builtin_amdgcn_mfma_f32_16x16x32_bf16(k1, qf1, z, 0, 0, 0);
        st[nt] = z;
      }
      if (kb == qb) {  // diagonal: mask kpos_local > qrow_local
        const int rloc = wave * 16 + l15;
#pragma unroll
        for (int nt = 0; nt < 4; ++nt)
#pragma unroll
          for (int r = 0; r < 4; ++r)
            if (nt * 16 + quad * 4 + r > rloc) st[nt][r] = -1e30f;
      }

      // ---- row max over kpos: in-lane fold + cross-quad shfl ----
      float tm = st[0][0];
#pragma unroll
      for (int nt = 0; nt < 4; ++nt)
#pragma unroll
        for (int r = 0; r < 4; ++r) tm = fmaxf(tm, st[nt][r]);
      tm = fmaxf(tm, __shfl_xor(tm, 16));
      tm = fmaxf(tm, __shfl_xor(tm, 32));
      const float mn = fmaxf(m_r, tm * C2);
      const float alpha = __builtin_amdgcn_exp2f(m_r - mn);
      m_r = mn;

      // ---- P = exp2(fma(st,C2,-m)); pack bf16x4 -> b64 write ----
#pragma unroll
      for (int nt = 0; nt < 4; ++nt) {
        float p0 = __builtin_amdgcn_exp2f(__builtin_fmaf(st[nt][0], C2, -mn));
        float p1 = __builtin_amdgcn_exp2f(__builtin_fmaf(st[nt][1], C2, -mn));
        float p2 = __builtin_amdgcn_exp2f(__builtin_fmaf(st[nt][2], C2, -mn));
        float p3 = __builtin_amdgcn_exp2f(__builtin_fmaf(st[nt][3], C2, -mn));
        uint2 w;
        w.x = pack_bf2(p0, p1);
        w.y = pack_bf2(p2, p3);
        *(uint2*)(&Plds[wave][l15][nt * 16 + quad * 4]) = w;
      }

      // ---- O *= alpha ----
#pragma unroll
      for (int dt = 0; dt < 4; ++dt)
#pragma unroll
        for (int r = 0; r < 4; ++r) o[dt][r] *= alpha;

      // ---- P as B-frags (same-wave round trip, DS in-order) ----
      short8 pB0 = *(const short8*)(&Plds[wave][l15][quad * 8]);
      short8 pB1 = *(const short8*)(&Plds[wave][l15][32 + quad * 8]);

      // row sums via ones-MFMA
      f32x4 ps = {};
      ps = __builtin_amdgcn_mfma_f32_16x16x32_bf16(ones, pB0, ps, 0, 0, 0);
      ps = __builtin_amdgcn_mfma_f32_16x16x32_bf16(ones, pB1, ps, 0, 0, 0);
      l_r = alpha * l_r + ps[0];

      // ---- O^T += V^T P : V frags direct from global ----
#pragma unroll
      for (int dt = 0; dt < 4; ++dt) {
        short8 v0 = *(const short8*)(vp + (size_t)(dt * 16) * S_);
        short8 v1 = *(const short8*)(vp + (size_t)(dt * 16) * S_ + 32);
        o[dt] = __builtin_amdgcn_mfma_f32_16x16x32_bf16(v0, pB0, o[dt], 0, 0, 0);
        o[dt] = __builtin_amdgcn_mfma_f32_16x16x32_bf16(v1, pB1, o[dt], 0, 0, 0);
      }
      // no __syncthreads: Plds is per-wave, K/V come from global
    }

    // ---- epilogue: ctx[qrow][d] = O^T/l, packed b64 stores ----
    const float rl = __builtin_amdgcn_rcpf(l_r);
    __hip_bfloat16* crow = ctx + ((size_t)b * S_ + qrow) * D_ + h * HD_;
#pragma unroll
    for (int dt = 0; dt < 4; ++dt) {
      uint2 w;
      w.x = pack_bf2(o[dt][0] * rl, o[dt][1] * rl);
      w.y = pack_bf2(o[dt][2] * rl, o[dt][3] * rl);
      *(uint2*)(crow + dt * 16 + quad * 4) = w;
    }
  }
}

// --------------------------------------------------------------- launch ----
extern "C" void kernel_launch(void* const* d_in, const int* in_sizes, int n_in,
                              void* d_out, int out_size, void* d_ws,
                              size_t ws_size, hipStream_t stream) {
  const float* x      = (const float*)d_in[0];
  const float* w_qkv  = (const float*)d_in[1];
  const float* b_qkv  = (const float*)d_in[2];
  const float* w_proj = (const float*)d_in[3];
  const float* b_proj = (const float*)d_in[4];
  float* out = (float*)d_out;

  char* ws = (char*)d_ws;
  __hip_bfloat16* xb     = (__hip_bfloat16*)(ws + 0);          // 16 MB
  __hip_bfloat16* wqkvT  = (__hip_bfloat16*)(ws + 16777216);   // 6 MB
  __hip_bfloat16* wprojT = (__hip_bfloat16*)(ws + 23068672);   // 2 MB
  __hip_bfloat16* qkvb   = (__hip_bfloat16*)(ws + 25165824);   // 50.3 MB
  __hip_bfloat16* ctx    = (__hip_bfloat16*)(ws + 75497472);   // 16 MB
  __hip_bfloat16* vt2    = (__hip_bfloat16*)(ws + 91750400);   // 16 MB

  cast_f32_bf16<<<8192, 256, 0, stream>>>(x, xb, M_ * D_);
  transpose_cast<<<dim3(N3_ / 32, D_ / 32), dim3(32, 8), 0, stream>>>(
      w_qkv, wqkvT, D_, N3_);
  transpose_cast<<<dim3(D_ / 32, D_ / 32), dim3(32, 8), 0, stream>>>(
      w_proj, wprojT, D_, D_);

  gemm_bt_bias<__hip_bfloat16, true>
      <<<dim3(N3_ / 128, M_ / 128), 256, 0, stream>>>(
          xb, wqkvT, b_qkv, qkvb, vt2, M_, N3_, D_);

  attn_causal<<<dim3(16, H_, B_), 256, 0, stream>>>(qkvb, vt2, ctx);

  gemm_bt_bias<float, false><<<dim3(D_ / 128, M_ / 128), 256, 0, stream>>>(
      ctx, wprojT, b_proj, out, (__hip_bfloat16*)nullptr, M_, D_, D_);
}

// Round 7
// 285.205 us; speedup vs baseline: 1.5314x; 1.5314x over previous
//
#include <hip/hip_runtime.h>
#include <hip/hip_bf16.h>

typedef __attribute__((ext_vector_type(8))) short short8;
typedef __attribute__((ext_vector_type(4))) float f32x4;

#define B_   4
#define S_   2048
#define D_   1024
#define H_   16
#define HD_  64
#define M_   (B_ * S_)      // 8192
#define N3_  (3 * D_)       // 3072

#define GLDS16(g, l)                                                        \
  __builtin_amdgcn_global_load_lds(                                         \
      (const __attribute__((address_space(1))) void*)(g),                   \
      (__attribute__((address_space(3))) void*)(l), 16, 0, 0)

__device__ __forceinline__ unsigned pack_bf2(float a, float b) {
  union { __hip_bfloat16 h; unsigned short s; } ua, ub;
  ua.h = __float2bfloat16(a);
  ub.h = __float2bfloat16(b);
  return (unsigned)ua.s | ((unsigned)ub.s << 16);
}

// ---------------------------------------------------------------- casts ----
__global__ __launch_bounds__(256) void cast_f32_bf16(
    const float* __restrict__ in, __hip_bfloat16* __restrict__ out, int n) {
  int i = (blockIdx.x * 256 + threadIdx.x) * 4;
  if (i + 3 < n) {
    float4 v = *(const float4*)(in + i);
    union { ushort4 u4; __hip_bfloat16 h[4]; } p;
    p.h[0] = __float2bfloat16(v.x);
    p.h[1] = __float2bfloat16(v.y);
    p.h[2] = __float2bfloat16(v.z);
    p.h[3] = __float2bfloat16(v.w);
    *(ushort4*)(out + i) = p.u4;
  }
}

// in: [rows][cols] fp32 -> out: [cols][rows] bf16
__global__ __launch_bounds__(256) void transpose_cast(
    const float* __restrict__ in, __hip_bfloat16* __restrict__ out,
    int rows, int cols) {
  __shared__ float tile[32][33];
  int bx = blockIdx.x * 32;
  int by = blockIdx.y * 32;
  int tx = threadIdx.x, ty = threadIdx.y;   // (32, 8)
#pragma unroll
  for (int i = 0; i < 4; ++i)
    tile[ty + i * 8][tx] = in[(size_t)(by + ty + i * 8) * cols + bx + tx];
  __syncthreads();
#pragma unroll
  for (int i = 0; i < 4; ++i)
    out[(size_t)(bx + ty + i * 8) * rows + by + tx] =
        __float2bfloat16(tile[tx][ty + i * 8]);
}

// ----------------------------------------------------------------- GEMM ----
// C[M][N] = A[M][K]*Bt[N][K]^T + bias.  128x128 tile, BK=64, GLDS16 staging
// into unpadded [128][64] LDS, XOR-8 swizzle on 16B column units.
// WVT: for output cols >= 2048 (the V slice of qkv), write transposed into
// vt[(b*16+h)][d][S] instead of C (fuses the old transpose_v kernel).
__device__ inline void store_out(float* p, float v) { *p = v; }
__device__ inline void store_out(__hip_bfloat16* p, float v) {
  *p = __float2bfloat16(v);
}

template <typename OUT_T, bool WVT>
__global__ __launch_bounds__(256) void gemm_bt_bias(
    const __hip_bfloat16* __restrict__ A, const __hip_bfloat16* __restrict__ Bt,
    const float* __restrict__ bias, OUT_T* __restrict__ C,
    __hip_bfloat16* __restrict__ vt, int M, int N, int K) {
  __shared__ __align__(16) __hip_bfloat16 Alds[128 * 64];
  __shared__ __align__(16) __hip_bfloat16 Blds[128 * 64];
  const int t = threadIdx.x;
  const int wave = t >> 6, lane = t & 63;
  const int quad = lane >> 4, l15 = lane & 15;
  const int wm = (wave >> 1) * 64, wn = (wave & 1) * 64;
  const int m0 = blockIdx.y * 128, n0 = blockIdx.x * 128;

  const int rsub = lane >> 3;
  const int gc16 = (lane & 7) ^ (rsub & 7);
  const __hip_bfloat16* gA[4];
  const __hip_bfloat16* gB[4];
  __hip_bfloat16* lA[4];
  __hip_bfloat16* lB[4];
#pragma unroll
  for (int i = 0; i < 4; ++i) {
    int c = wave * 4 + i;
    int row = c * 8 + rsub;
    gA[i] = A + (size_t)(m0 + row) * K + gc16 * 8;
    gB[i] = Bt + (size_t)(n0 + row) * K + gc16 * 8;
    lA[i] = Alds + c * 512;
    lB[i] = Blds + c * 512;
  }

  f32x4 acc[4][4] = {};

  for (int k0 = 0; k0 < K; k0 += 64) {
#pragma unroll
    for (int i = 0; i < 4; ++i) {
      GLDS16(gA[i] + k0, lA[i]);
      GLDS16(gB[i] + k0, lB[i]);
    }
    __syncthreads();
#pragma unroll
    for (int kk = 0; kk < 2; ++kk) {
      const int fo = ((kk * 4 + quad) ^ (l15 & 7)) * 8;  // swizzled frag col
      short8 a[4], bfr[4];
#pragma unroll
      for (int mt = 0; mt < 4; ++mt)
        a[mt] = *(const short8*)(Alds + (wm + mt * 16 + l15) * 64 + fo);
#pragma unroll
      for (int nt = 0; nt < 4; ++nt)
        bfr[nt] = *(const short8*)(Blds + (wn + nt * 16 + l15) * 64 + fo);
#pragma unroll
      for (int mt = 0; mt < 4; ++mt)
#pragma unroll
        for (int nt = 0; nt < 4; ++nt)
          acc[mt][nt] = __builtin_amdgcn_mfma_f32_16x16x32_bf16(
              a[mt], bfr[nt], acc[mt][nt], 0, 0, 0);
    }
    __syncthreads();
  }

  if (WVT && n0 >= 2048) {
#pragma unroll
    for (int mt = 0; mt < 4; ++mt)
#pragma unroll
      for (int nt = 0; nt < 4; ++nt) {
        int col = n0 + wn + nt * 16 + l15;
        float bv = bias[col];
        int hv = (col - 2048) >> 6, d = (col - 2048) & 63;
        int row0 = m0 + wm + mt * 16 + quad * 4;
        int bidx = row0 >> 11, s = row0 & 2047;
        uint2 w;
        w.x = pack_bf2(acc[mt][nt][0] + bv, acc[mt][nt][1] + bv);
        w.y = pack_bf2(acc[mt][nt][2] + bv, acc[mt][nt][3] + bv);
        *(uint2*)(vt + ((size_t)(bidx * 16 + hv) * 64 + d) * 2048 + s) = w;
      }
  } else {
#pragma unroll
    for (int mt = 0; mt < 4; ++mt)
#pragma unroll
      for (int nt = 0; nt < 4; ++nt) {
        int col = n0 + wn + nt * 16 + l15;
        float bv = bias[col];
#pragma unroll
        for (int r = 0; r < 4; ++r) {
          int row = m0 + wm + mt * 16 + quad * 4 + r;
          store_out(C + (size_t)row * N + col, acc[mt][nt][r] + bv);
        }
      }
  }
}

// ------------------------------------------------------ flash attention ----
// S^T formulation, LDS-staged K/V (R5 base).  New: 128-thread blocks, each
// wave owns 32 q-rows via TWO Q B-fragments sharing one set of K/V A-frags
// -> K/V LDS frag-read bytes per q-row halve.  Grid stays 1024 blocks.
__global__ __launch_bounds__(128) void attn_causal(
    const __hip_bfloat16* __restrict__ qkv,
    const __hip_bfloat16* __restrict__ vt,
    __hip_bfloat16* __restrict__ ctx) {
  __shared__ __align__(16) __hip_bfloat16 Klds[64][72];       // [kpos][d]
  __shared__ __align__(16) __hip_bfloat16 Vlds[64][72];       // [d][kpos]
  __shared__ __align__(16) __hip_bfloat16 Plds[2][2][16][72]; // [wave][g][qrow][kpos]

  const int t = threadIdx.x;
  const int wave = t >> 6, lane = t & 63;   // wave in {0,1}
  const int quad = lane >> 4, l15 = lane & 15;
  const int xb = blockIdx.x, h = blockIdx.y, b = blockIdx.z;

  const size_t qbase = (size_t)b * S_ * N3_ + h * HD_;
  const size_t kbase = qbase + D_;
  const size_t vtbase = (size_t)(b * H_ + h) * HD_ * S_;
  const float C2 = 0.18033688f;  // (1/sqrt(64)) * log2(e)

  short8 ones;
#pragma unroll
  for (int j = 0; j < 8; ++j) ones[j] = (short)0x3F80;  // bf16 1.0

  for (int sel = 0; sel < 2; ++sel) {
    const int qb = sel ? (31 - xb) : xb;   // pair-balanced: 33 iters/block
    short8 qf[2][2];
#pragma unroll
    for (int g = 0; g < 2; ++g) {
      const int qrow = qb * 64 + wave * 32 + g * 16 + l15;
      qf[g][0] =
          *(const short8*)(qkv + qbase + (size_t)qrow * N3_ + quad * 8);
      qf[g][1] =
          *(const short8*)(qkv + qbase + (size_t)qrow * N3_ + 32 + quad * 8);
    }

    f32x4 o[2][4] = {};               // O^T per group
    float m_r[2] = {-1e30f, -1e30f}, l_r[2] = {0.f, 0.f};

    for (int kb = 0; kb <= qb; ++kb) {
      // ---- stage K [kpos][d], V^T [d][kpos] (128 thr, b128) ----
#pragma unroll
      for (int i = 0; i < 4; ++i) {
        int c = t + 128 * i;
        int row = c >> 3, seg = c & 7;
        *(uint4*)(&Klds[row][seg * 8]) = *(const uint4*)(
            qkv + kbase + (size_t)(kb * 64 + row) * N3_ + seg * 8);
        *(uint4*)(&Vlds[row][seg * 8]) = *(const uint4*)(
            vt + vtbase + (size_t)row * S_ + kb * 64 + seg * 8);
      }
      __syncthreads();

      // ---- K A-frags once, reused by both Q groups ----
      short8 kf[4][2];
#pragma unroll
      for (int nt = 0; nt < 4; ++nt) {
        kf[nt][0] = *(const short8*)(&Klds[nt * 16 + l15][quad * 8]);
        kf[nt][1] = *(const short8*)(&Klds[nt * 16 + l15][32 + quad * 8]);
      }

      const bool diag = (kb == qb);
#pragma unroll
      for (int g = 0; g < 2; ++g) {
        f32x4 st[4];
#pragma unroll
        for (int nt = 0; nt < 4; ++nt) {
          f32x4 z = {};
          z = __builtin_amdgcn_mfma_f32_16x16x32_bf16(kf[nt][0], qf[g][0], z,
                                                      0, 0, 0);
          z = __builtin_amdgcn_mfma_f32_16x16x32_bf16(kf[nt][1], qf[g][1], z,
                                                      0, 0, 0);
          st[nt] = z;
        }
        if (diag) {  // mask kpos_local > qrow_local
          const int rloc = wave * 32 + g * 16 + l15;
#pragma unroll
          for (int nt = 0; nt < 4; ++nt)
#pragma unroll
            for (int r = 0; r < 4; ++r)
              if (nt * 16 + quad * 4 + r > rloc) st[nt][r] = -1e30f;
        }

        // row max over kpos: in-lane fold + cross-quad shfl
        float tm = st[0][0];
#pragma unroll
        for (int nt = 0; nt < 4; ++nt)
#pragma unroll
          for (int r = 0; r < 4; ++r) tm = fmaxf(tm, st[nt][r]);
        tm = fmaxf(tm, __shfl_xor(tm, 16));
        tm = fmaxf(tm, __shfl_xor(tm, 32));
        const float mn = fmaxf(m_r[g], tm * C2);
        const float alpha = __builtin_amdgcn_exp2f(m_r[g] - mn);
        m_r[g] = mn;
        l_r[g] *= alpha;

        // P = exp2(fma(st,C2,-m)); pack bf16x4 -> b64 write
#pragma unroll
        for (int nt = 0; nt < 4; ++nt) {
          float p0 = __builtin_amdgcn_exp2f(__builtin_fmaf(st[nt][0], C2, -mn));
          float p1 = __builtin_amdgcn_exp2f(__builtin_fmaf(st[nt][1], C2, -mn));
          float p2 = __builtin_amdgcn_exp2f(__builtin_fmaf(st[nt][2], C2, -mn));
          float p3 = __builtin_amdgcn_exp2f(__builtin_fmaf(st[nt][3], C2, -mn));
          uint2 w;
          w.x = pack_bf2(p0, p1);
          w.y = pack_bf2(p2, p3);
          *(uint2*)(&Plds[wave][g][l15][nt * 16 + quad * 4]) = w;
        }

        // O *= alpha
#pragma unroll
        for (int dt = 0; dt < 4; ++dt)
#pragma unroll
          for (int r = 0; r < 4; ++r) o[g][dt][r] *= alpha;
      }

      // ---- P B-frags (same-wave round trip); V frags once, both groups ----
      short8 pB[2][2];
#pragma unroll
      for (int g = 0; g < 2; ++g) {
        pB[g][0] = *(const short8*)(&Plds[wave][g][l15][quad * 8]);
        pB[g][1] = *(const short8*)(&Plds[wave][g][l15][32 + quad * 8]);
        f32x4 ps = {};
        ps = __builtin_amdgcn_mfma_f32_16x16x32_bf16(ones, pB[g][0], ps, 0, 0, 0);
        ps = __builtin_amdgcn_mfma_f32_16x16x32_bf16(ones, pB[g][1], ps, 0, 0, 0);
        l_r[g] += ps[0];
      }

#pragma unroll
      for (int dt = 0; dt < 4; ++dt) {
        short8 v0 = *(const short8*)(&Vlds[dt * 16 + l15][quad * 8]);
        short8 v1 = *(const short8*)(&Vlds[dt * 16 + l15][32 + quad * 8]);
#pragma unroll
        for (int g = 0; g < 2; ++g) {
          o[g][dt] = __builtin_amdgcn_mfma_f32_16x16x32_bf16(v0, pB[g][0],
                                                             o[g][dt], 0, 0, 0);
          o[g][dt] = __builtin_amdgcn_mfma_f32_16x16x32_bf16(v1, pB[g][1],
                                                             o[g][dt], 0, 0, 0);
        }
      }
      __syncthreads();  // before next iter overwrites Klds/Vlds
    }

    // ---- epilogue: ctx[qrow][d] = O^T/l, packed b64 stores ----
#pragma unroll
    for (int g = 0; g < 2; ++g) {
      const float rl = __builtin_amdgcn_rcpf(l_r[g]);
      const int qrow = qb * 64 + wave * 32 + g * 16 + l15;
      __hip_bfloat16* crow = ctx + ((size_t)b * S_ + qrow) * D_ + h * HD_;
#pragma unroll
      for (int dt = 0; dt < 4; ++dt) {
        uint2 w;
        w.x = pack_bf2(o[g][dt][0] * rl, o[g][dt][1] * rl);
        w.y = pack_bf2(o[g][dt][2] * rl, o[g][dt][3] * rl);
        *(uint2*)(crow + dt * 16 + quad * 4) = w;
      }
    }
  }
}

// --------------------------------------------------------------- launch ----
extern "C" void kernel_launch(void* const* d_in, const int* in_sizes, int n_in,
                              void* d_out, int out_size, void* d_ws,
                              size_t ws_size, hipStream_t stream) {
  const float* x      = (const float*)d_in[0];
  const float* w_qkv  = (const float*)d_in[1];
  const float* b_qkv  = (const float*)d_in[2];
  const float* w_proj = (const float*)d_in[3];
  const float* b_proj = (const float*)d_in[4];
  float* out = (float*)d_out;

  char* ws = (char*)d_ws;
  __hip_bfloat16* xb     = (__hip_bfloat16*)(ws + 0);          // 16 MB
  __hip_bfloat16* wqkvT  = (__hip_bfloat16*)(ws + 16777216);   // 6 MB
  __hip_bfloat16* wprojT = (__hip_bfloat16*)(ws + 23068672);   // 2 MB
  __hip_bfloat16* qkvb   = (__hip_bfloat16*)(ws + 25165824);   // 50.3 MB
  __hip_bfloat16* ctx    = (__hip_bfloat16*)(ws + 75497472);   // 16 MB
  __hip_bfloat16* vt2    = (__hip_bfloat16*)(ws + 91750400);   // 16 MB

  cast_f32_bf16<<<8192, 256, 0, stream>>>(x, xb, M_ * D_);
  transpose_cast<<<dim3(N3_ / 32, D_ / 32), dim3(32, 8), 0, stream>>>(
      w_qkv, wqkvT, D_, N3_);
  transpose_cast<<<dim3(D_ / 32, D_ / 32), dim3(32, 8), 0, stream>>>(
      w_proj, wprojT, D_, D_);

  gemm_bt_bias<__hip_bfloat16, true>
      <<<dim3(N3_ / 128, M_ / 128), 256, 0, stream>>>(
          xb, wqkvT, b_qkv, qkvb, vt2, M_, N3_, D_);

  attn_causal<<<dim3(16, H_, B_), 128, 0, stream>>>(qkvb, vt2, ctx);

  gemm_bt_bias<float, false><<<dim3(D_ / 128, M_ / 128), 256, 0, stream>>>(
      ctx, wprojT, b_proj, out, (__hip_bfloat16*)nullptr, M_, D_, D_);
}